// Round 1
// 475.841 us; speedup vs baseline: 1.4474x; 1.4474x over previous
//
#include <hip/hip_runtime.h>

typedef __attribute__((ext_vector_type(8))) _Float16 half8;
typedef __attribute__((ext_vector_type(16))) float f32x16;

#define TOK 98
#define QSCALE 0.17677669529663687f  // 1/sqrt(32)

// LDS layout in _Float16 units.
//  Qs: [98][40]   at 0      (rows m, cols d<32, 80B stride, 16B aligned)
//  Ks: [98][40]   at 3920
//  Ps: [98][120]  at 0      (overlaps Qs+Ks; written only after QK reads done)
//  Vt: [32][120]  at 11760  (V TRANSPOSED: Vt[d][token]; tokens 98..111 zeroed)
#define QS 0
#define KS 3920
#define PS 0
#define VT 11760
#define LDSH (11760 + 32 * 120)   // 15600 halves = 31200 B

__device__ inline half8 cvt8(float4 a, float4 b) {
    half8 r;
    r[0] = (_Float16)a.x; r[1] = (_Float16)a.y; r[2] = (_Float16)a.z; r[3] = (_Float16)a.w;
    r[4] = (_Float16)b.x; r[5] = (_Float16)b.y; r[6] = (_Float16)b.z; r[7] = (_Float16)b.w;
    return r;
}

__global__ __launch_bounds__(256, 3) void attn_mfma(
    const float* __restrict__ x,       // [B][98][128]
    const float* __restrict__ mask,    // [L][98][98]
    const float* __restrict__ qkv_w,   // [384][128]
    const float* __restrict__ qkv_b,   // [384]
    const float* __restrict__ rel,     // [4][507]
    float* __restrict__ out,           // [B][98][128] (pre-proj)
    int Lmask)
{
    __shared__ __align__(16) _Float16 lh[LDSH];
    __shared__ float rel_lds[507];

    const int tid  = threadIdx.x;

    // XCD-bijective swizzle: blocks hw, hw+8, hw+16,... share an XCD's L2.
    // Groups the 4 heads of each window (consecutive works) on one XCD.
    int wg = (int)blockIdx.x;
    int work;
    if ((gridDim.x & 7) == 0) {
        int cpx = gridDim.x >> 3;
        work = (wg & 7) * cpx + (wg >> 3);
    } else {
        work = wg;
    }
    const int b    = work >> 2;
    const int h    = work & 3;

    const int wv   = tid >> 6;        // wave 0..3: owns token rows [32wv, 32wv+32)
    const int lane = tid & 63;
    const int t32  = lane & 31;
    const int half = lane >> 5;

    // stage rel row for this head; zero Vt pad cols 98..111 (PV k-padding)
    for (int i = tid; i < 507; i += 256) rel_lds[i] = rel[h * 507 + i];
    for (int i = tid; i < 32 * 14; i += 256) {
        int d = i / 14, m = i - 14 * d;
        lh[VT + d * 120 + 98 + m] = (_Float16)0.f;
    }

    // ---------------- Stage 1: qkv slice GEMM via fp16 MFMA ----------------
    int tok = 32 * wv + t32; if (tok > 97) tok = 97;   // clamp: dup rows discarded
    const float* xrow = x + ((long)b * TOK + tok) * 128 + half * 8;

    f32x16 acc[3];
#pragma unroll
    for (int nt = 0; nt < 3; nt++)
#pragma unroll
        for (int i = 0; i < 16; i++) acc[nt][i] = 0.f;

#pragma unroll
    for (int kt = 0; kt < 8; ++kt) {
        float4 a0 = *(const float4*)(xrow + kt * 16);
        float4 a1 = *(const float4*)(xrow + kt * 16 + 4);
        half8 af = cvt8(a0, a1);
#pragma unroll
        for (int nt = 0; nt < 3; nt++) {
            const float* wr = qkv_w + ((long)(nt * 128 + h * 32 + t32)) * 128 + kt * 16 + half * 8;
            float4 b0 = *(const float4*)wr;
            float4 b1 = *(const float4*)(wr + 4);
            half8 bf = cvt8(b0, b1);
            acc[nt] = __builtin_amdgcn_mfma_f32_32x32x16_f16(af, bf, acc[nt], 0, 0, 0);
        }
    }

    // store Q (scaled+bias), K to LDS row-major; V TRANSPOSED Vt[d][m].
    // C/D layout: col=lane&31, row=(reg&3)+8*(reg>>2)+4*half
    {
        const float qb = qkv_b[h * 32 + t32];
        const float kb = qkv_b[128 + h * 32 + t32];
        const float vb = qkv_b[256 + h * 32 + t32];
#pragma unroll
        for (int reg = 0; reg < 16; ++reg) {
            int m = 32 * wv + (reg & 3) + 8 * (reg >> 2) + 4 * half;
            if (m < TOK) {
                lh[QS + m * 40 + t32]  = (_Float16)((acc[0][reg] + qb) * QSCALE);
                lh[KS + m * 40 + t32]  = (_Float16)(acc[1][reg] + kb);
                lh[VT + t32 * 120 + m] = (_Float16)(acc[2][reg] + vb);   // transposed
            }
        }
    }

    // ---------------- Mask burst: issue ALL 64 loads before barrier ----------
    // Unconditional, clamped addresses -> one pipelined drain, latency hidden
    // under barrier + stage 2. Validity applied later via select.
    const long mbase = (long)(b % Lmask) * (TOK * TOK);
    const int mrow0 = 32 * wv + 4 * half;

    int jterm[4]; bool jvld[4];
    float mv[4][16];
#pragma unroll
    for (int nt = 0; nt < 4; ++nt) {
        int j = nt * 32 + t32;
        jvld[nt] = (j < TOK);
        int jc = jvld[nt] ? j : 97;
        int tj = jc / 49; int rj = jc - 49 * tj; int hj = rj / 7; int wj = rj - 7 * hj;
        jterm[nt] = tj * 169 + hj * 13 + wj;
        const float* mc = mask + mbase + jc;
#pragma unroll
        for (int reg = 0; reg < 16; ++reg) {
            int m = mrow0 + (reg & 3) + 8 * (reg >> 2);
            int mm = m > 97 ? 97 : m;
            mv[nt][reg] = mc[(long)mm * TOK];
        }
    }

    __syncthreads();

    // ---------------- Stage 2: S = Q K^T (rows [32wv,32wv+32), all 128 cols) ----
    f32x16 sacc[4];
#pragma unroll
    for (int nt = 0; nt < 4; nt++)
#pragma unroll
        for (int i = 0; i < 16; i++) sacc[nt][i] = 0.f;

#pragma unroll
    for (int kk = 0; kk < 2; ++kk) {
        half8 qa = *(const half8*)&lh[QS + tok * 40 + kk * 16 + half * 8];
#pragma unroll
        for (int nt = 0; nt < 4; ++nt) {
            int kr = nt * 32 + t32; if (kr > 97) kr = 97;   // dup cols masked later
            half8 kf = *(const half8*)&lh[KS + kr * 40 + kk * 16 + half * 8];
            sacc[nt] = __builtin_amdgcn_mfma_f32_32x32x16_f16(qa, kf, sacc[nt], 0, 0, 0);
        }
    }
    __syncthreads();   // all Qs/Ks reads done; Ps (overlapping) may now be written

    // ---------------- Stage 3: bias + mask + softmax ----------------
#pragma unroll
    for (int reg = 0; reg < 16; ++reg) {
        int m = mrow0 + (reg & 3) + 8 * (reg >> 2);
        bool mok = (m < TOK);
        int mm = mok ? m : 97;
        int ti = mm / 49; int r2 = mm - 49 * ti; int hi = r2 / 7; int wi = r2 - 7 * hi;
        // offset 253 = 1*169 + 6*13 + 6 so that mterm - jterm == REL_IDX[m][j]
        int mterm = ti * 169 + hi * 13 + wi + 253;
#pragma unroll
        for (int nt = 0; nt < 4; ++nt) {
            float s = sacc[nt][reg] + rel_lds[mterm - jterm[nt]] + mv[nt][reg];
            sacc[nt][reg] = (mok && jvld[nt]) ? s : -1e30f;
        }
    }

    float rmax[16], rsum[16];
#pragma unroll
    for (int reg = 0; reg < 16; ++reg) {
        float v = fmaxf(fmaxf(sacc[0][reg], sacc[1][reg]), fmaxf(sacc[2][reg], sacc[3][reg]));
        v = fmaxf(v, __shfl_xor(v, 1));
        v = fmaxf(v, __shfl_xor(v, 2));
        v = fmaxf(v, __shfl_xor(v, 4));
        v = fmaxf(v, __shfl_xor(v, 8));
        v = fmaxf(v, __shfl_xor(v, 16));
        rmax[reg] = v;
        rsum[reg] = 0.f;
    }

#pragma unroll
    for (int nt = 0; nt < 4; ++nt) {
        int j = nt * 32 + t32;
#pragma unroll
        for (int reg = 0; reg < 16; ++reg) {
            int m = mrow0 + (reg & 3) + 8 * (reg >> 2);
            float p = __expf(sacc[nt][reg] - rmax[reg]);
            rsum[reg] += p;
            if (m < TOK && j < 112) lh[PS + m * 120 + j] = (_Float16)p; // pad cols -> 0 naturally
        }
    }

#pragma unroll
    for (int reg = 0; reg < 16; ++reg) {
        float v = rsum[reg];
        v += __shfl_xor(v, 1);
        v += __shfl_xor(v, 2);
        v += __shfl_xor(v, 4);
        v += __shfl_xor(v, 8);
        v += __shfl_xor(v, 16);
        rsum[reg] = 1.0f / v;
    }

    // ---------------- Stage 4: O = P V  (both operands as b128 reads) ----
    f32x16 oacc;
#pragma unroll
    for (int i = 0; i < 16; i++) oacc[i] = 0.f;

#pragma unroll
    for (int kk = 0; kk < 7; ++kk) {
        half8 pa = *(const half8*)&lh[PS + tok * 120 + kk * 16 + half * 8];
        half8 vf = *(const half8*)&lh[VT + t32 * 120 + kk * 16 + half * 8];
        oacc = __builtin_amdgcn_mfma_f32_32x32x16_f16(pa, vf, oacc, 0, 0, 0);
    }

    float* ob = out + ((long)b * TOK) * 128 + h * 32 + t32;
#pragma unroll
    for (int reg = 0; reg < 16; ++reg) {
        int m = mrow0 + (reg & 3) + 8 * (reg >> 2);
        if (m < TOK) ob[(long)m * 128] = oacc[reg] * rsum[reg];
    }
}

// ---------------- Proj GEMM, in-place on d_out, fp16 MFMA ----------------
// proj_w staged once per block as fp16 in LDS (stride 136 -> conflict-free b128).
__global__ __launch_bounds__(256, 4) void proj_mfma(
    const float* __restrict__ proj_w,  // [128][128]
    const float* __restrict__ proj_b,  // [128]
    float* __restrict__ out,
    int totalRows)
{
    __shared__ __align__(16) _Float16 wl[128 * 136];

    const int tid  = threadIdx.x;
    const int wv   = tid >> 6;
    const int lane = tid & 63;
    const int t32  = lane & 31;
    const int half = lane >> 5;

    // cooperative fp32->fp16 staging of proj_w: each thread one half-row (64 cols)
    {
        int row = tid & 127, c0 = (tid >> 7) * 64;
        const float* src = proj_w + row * 128 + c0;
        _Float16* dst = &wl[row * 136 + c0];
#pragma unroll
        for (int i = 0; i < 8; ++i) {
            float4 a = *(const float4*)(src + i * 8);
            float4 b2 = *(const float4*)(src + i * 8 + 4);
            *(half8*)(dst + i * 8) = cvt8(a, b2);
        }
    }

    const long rowb = (long)blockIdx.x * 128 + 32 * wv;
    long rr = rowb + t32; if (rr >= totalRows) rr = totalRows - 1;
    const float* arow = out + rr * 128 + half * 8;

    half8 af[8];
#pragma unroll
    for (int kt = 0; kt < 8; ++kt) {
        float4 a0 = *(const float4*)(arow + kt * 16);
        float4 a1 = *(const float4*)(arow + kt * 16 + 4);
        af[kt] = cvt8(a0, a1);
    }

    __syncthreads();

    f32x16 acc[4];
#pragma unroll
    for (int nt = 0; nt < 4; nt++)
#pragma unroll
        for (int i = 0; i < 16; i++) acc[nt][i] = 0.f;

#pragma unroll
    for (int kt = 0; kt < 8; ++kt) {
#pragma unroll
        for (int nt = 0; nt < 4; ++nt) {
            half8 bf = *(const half8*)&wl[(nt * 32 + t32) * 136 + kt * 16 + half * 8];
            acc[nt] = __builtin_amdgcn_mfma_f32_32x32x16_f16(af[kt], bf, acc[nt], 0, 0, 0);
        }
    }

#pragma unroll
    for (int nt = 0; nt < 4; ++nt) {
        int co = nt * 32 + t32;
        float pb = proj_b[co];
#pragma unroll
        for (int reg = 0; reg < 16; ++reg) {
            long m = rowb + (reg & 3) + 8 * (reg >> 2) + 4 * half;
            if (m < totalRows) out[m * 128 + co] = acc[nt][reg] + pb;
        }
    }
}

extern "C" void kernel_launch(void* const* d_in, const int* in_sizes, int n_in,
                              void* d_out, int out_size, void* d_ws, size_t ws_size,
                              hipStream_t stream) {
    const float* x      = (const float*)d_in[0];
    const float* mask   = (const float*)d_in[1];
    const float* qkv_w  = (const float*)d_in[2];
    const float* qkv_b  = (const float*)d_in[3];
    const float* rel    = (const float*)d_in[4];
    const float* proj_w = (const float*)d_in[5];
    const float* proj_b = (const float*)d_in[6];
    float* out = (float*)d_out;

    const int B     = in_sizes[0] / (TOK * 128);
    const int Lmask = in_sizes[1] / (TOK * TOK);

    attn_mfma<<<B * 4, 256, 0, stream>>>(x, mask, qkv_w, qkv_b, rel, out, Lmask);

    const int totalRows = B * TOK;
    proj_mfma<<<(totalRows + 127) / 128, 256, 0, stream>>>(proj_w, proj_b, out, totalRows);
}

// Round 2
// 441.552 us; speedup vs baseline: 1.5599x; 1.0777x over previous
//
#include <hip/hip_runtime.h>

typedef __attribute__((ext_vector_type(8))) _Float16 half8;
typedef __attribute__((ext_vector_type(16))) float f32x16;

#define TOK 98
#define QSCALE 0.17677669529663687f  // 1/sqrt(32)

// LDS layout in _Float16 units (attn kernel).
//  XL: [98][132] at 0      x staged fp16 (dead after stage 1)
//  PS: [98][120] at 0      overlays XL (written after stage-2 barrier epoch)
//  QS: [98][40]  at 12936
//  KS: [98][40]  at 16856
//  VT: [32][132] at 20776  V transposed Vt[d][token]; tokens 98..111 zeroed
#define XL 0
#define PS 0
#define XSTR 132
#define QS 12936
#define KS 16856
#define VT 20776
#define VSTR 132
#define LDSH (20776 + 32 * 132)   // 25000 halves = 50000 B

__device__ inline half8 cvt8(float4 a, float4 b) {
    half8 r;
    r[0] = (_Float16)a.x; r[1] = (_Float16)a.y; r[2] = (_Float16)a.z; r[3] = (_Float16)a.w;
    r[4] = (_Float16)b.x; r[5] = (_Float16)b.y; r[6] = (_Float16)b.z; r[7] = (_Float16)b.w;
    return r;
}

// ---------------- Prep: fp32 -> fp16 weight conversion (once per call) ------
// w16[0..49152)    = qkv_w fp16
// w16[49152..65536)= proj_w fp16
__global__ void prep_w(const float* __restrict__ qkv_w,
                       const float* __restrict__ proj_w,
                       _Float16* __restrict__ w16)
{
    int i = blockIdx.x * 256 + threadIdx.x;   // grid exactly 65536 threads
    if (i < 49152) w16[i] = (_Float16)qkv_w[i];
    else           w16[i] = (_Float16)proj_w[i - 49152];
}

__global__ __launch_bounds__(256, 3) void attn_mfma(
    const float* __restrict__ x,       // [B][98][128]
    const float* __restrict__ mask,    // [L][98][98]
    const float* __restrict__ qkv_b,   // [384]
    const float* __restrict__ rel,     // [4][507]
    const _Float16* __restrict__ qkv16,// [384][128] fp16
    float* __restrict__ out,           // [B][98][128] (pre-proj, fp32 path)
    _Float16* __restrict__ o16,        // [B][98][128] fp16 (ws path)
    int Lmask, int useO16)
{
    __shared__ __align__(16) _Float16 lh[LDSH];
    __shared__ float rel_lds[507];

    const int tid  = threadIdx.x;

    // XCD-bijective swizzle (grid % 8 == 0 in this problem).
    int wg = (int)blockIdx.x;
    int work;
    if ((gridDim.x & 7) == 0) {
        int cpx = gridDim.x >> 3;
        work = (wg & 7) * cpx + (wg >> 3);
    } else {
        work = wg;
    }
    const int b    = work >> 2;
    const int h    = work & 3;

    const int wv   = tid >> 6;        // wave 0..3: owns token rows [32wv, 32wv+32)
    const int lane = tid & 63;
    const int t32  = lane & 31;
    const int half = lane >> 5;

    // ---- stage rel row; zero Vt pad tokens 98..111; stage x fp16 coalesced ----
    for (int i = tid; i < 507; i += 256) rel_lds[i] = rel[h * 507 + i];
    for (int i = tid; i < 32 * 14; i += 256) {
        int d = i / 14, m = i - 14 * d;
        lh[VT + d * VSTR + 98 + m] = (_Float16)0.f;
    }
    // x[b]: 98 rows x 128 cols; chunk = 8 floats. Coalesced across lanes.
    for (int j = tid; j < TOK * 16; j += 256) {
        int row = j >> 4, c8 = (j & 15) << 3;
        const float* src = x + ((long)b * TOK + row) * 128 + c8;
        float4 a0 = *(const float4*)src;
        float4 a1 = *(const float4*)(src + 4);
        *(half8*)&lh[XL + row * XSTR + c8] = cvt8(a0, a1);
    }
    __syncthreads();   // barrier #1

    // ---------------- Stage 1: qkv slice GEMM (A from LDS, B fp16 global) ----
    int tok = 32 * wv + t32; if (tok > 97) tok = 97;   // clamp: dup rows discarded

    f32x16 acc[3];
#pragma unroll
    for (int nt = 0; nt < 3; nt++)
#pragma unroll
        for (int i = 0; i < 16; i++) acc[nt][i] = 0.f;

#pragma unroll
    for (int kt = 0; kt < 8; ++kt) {
        half8 af = *(const half8*)&lh[XL + tok * XSTR + kt * 16 + half * 8];
#pragma unroll
        for (int nt = 0; nt < 3; nt++) {
            const _Float16* wr = qkv16 + ((long)(nt * 128 + h * 32 + t32)) * 128 + kt * 16 + half * 8;
            half8 bf = *(const half8*)wr;
            acc[nt] = __builtin_amdgcn_mfma_f32_32x32x16_f16(af, bf, acc[nt], 0, 0, 0);
        }
    }

    // store Q (scaled+bias), K row-major; V transposed Vt[d][m].
    // C/D layout: col=lane&31, row=(reg&3)+8*(reg>>2)+4*half
    {
        const float qb = qkv_b[h * 32 + t32];
        const float kb = qkv_b[128 + h * 32 + t32];
        const float vb = qkv_b[256 + h * 32 + t32];
#pragma unroll
        for (int reg = 0; reg < 16; ++reg) {
            int m = 32 * wv + (reg & 3) + 8 * (reg >> 2) + 4 * half;
            if (m < TOK) {
                lh[QS + m * 40 + t32]   = (_Float16)((acc[0][reg] + qb) * QSCALE);
                lh[KS + m * 40 + t32]   = (_Float16)(acc[1][reg] + kb);
                lh[VT + t32 * VSTR + m] = (_Float16)(acc[2][reg] + vb);   // transposed
            }
        }
    }

    // ---------------- Mask burst: all 64 loads issued before the barrier ------
    const long mbase = (long)(b % Lmask) * (TOK * TOK);
    const int mrow0 = 32 * wv + 4 * half;

    int jterm[4]; bool jvld[4];
    float mv[4][16];
#pragma unroll
    for (int nt = 0; nt < 4; ++nt) {
        int j = nt * 32 + t32;
        jvld[nt] = (j < TOK);
        int jc = jvld[nt] ? j : 97;
        int tj = jc / 49; int rj = jc - 49 * tj; int hj = rj / 7; int wj = rj - 7 * hj;
        jterm[nt] = tj * 169 + hj * 13 + wj;
        const float* mc = mask + mbase + jc;
#pragma unroll
        for (int reg = 0; reg < 16; ++reg) {
            int m = mrow0 + (reg & 3) + 8 * (reg >> 2);
            int mm = m > 97 ? 97 : m;
            mv[nt][reg] = mc[(long)mm * TOK];
        }
    }

    __syncthreads();   // barrier #2 (Q/K/Vt visible to all waves)

    // ---------------- Stage 2: S = Q K^T ----------------
    f32x16 sacc[4];
#pragma unroll
    for (int nt = 0; nt < 4; nt++)
#pragma unroll
        for (int i = 0; i < 16; i++) sacc[nt][i] = 0.f;

#pragma unroll
    for (int kk = 0; kk < 2; ++kk) {
        half8 qa = *(const half8*)&lh[QS + tok * 40 + kk * 16 + half * 8];
#pragma unroll
        for (int nt = 0; nt < 4; ++nt) {
            int kr = nt * 32 + t32; if (kr > 97) kr = 97;   // dup cols masked later
            half8 kf = *(const half8*)&lh[KS + kr * 40 + kk * 16 + half * 8];
            sacc[nt] = __builtin_amdgcn_mfma_f32_32x32x16_f16(qa, kf, sacc[nt], 0, 0, 0);
        }
    }
    // NO barrier: P overlays XL (dead since stage 1); P rows are intra-wave.

    // ---------------- Stage 3: bias + mask + wave-max softmax ----------------
#pragma unroll
    for (int reg = 0; reg < 16; ++reg) {
        int m = mrow0 + (reg & 3) + 8 * (reg >> 2);
        bool mok = (m < TOK);
        int mm = mok ? m : 97;
        int ti = mm / 49; int r2 = mm - 49 * ti; int hi = r2 / 7; int wi = r2 - 7 * hi;
        // offset 253 = 1*169 + 6*13 + 6 so that mterm - jterm == REL_IDX[m][j]
        int mterm = ti * 169 + hi * 13 + wi + 253;
#pragma unroll
        for (int nt = 0; nt < 4; ++nt) {
            float s = sacc[nt][reg] + rel_lds[mterm - jterm[nt]] + mv[nt][reg];
            sacc[nt][reg] = (mok && jvld[nt]) ? s : -1e30f;
        }
    }

    // Wave-uniform max (valid for softmax: same constant for a whole row).
    float wm = -1e30f;
#pragma unroll
    for (int nt = 0; nt < 4; ++nt)
#pragma unroll
        for (int reg = 0; reg < 16; ++reg) wm = fmaxf(wm, sacc[nt][reg]);
    wm = fmaxf(wm, __shfl_xor(wm, 1));
    wm = fmaxf(wm, __shfl_xor(wm, 2));
    wm = fmaxf(wm, __shfl_xor(wm, 4));
    wm = fmaxf(wm, __shfl_xor(wm, 8));
    wm = fmaxf(wm, __shfl_xor(wm, 16));
    wm = fmaxf(wm, __shfl_xor(wm, 32));

#pragma unroll
    for (int nt = 0; nt < 4; ++nt) {
        int j = nt * 32 + t32;
#pragma unroll
        for (int reg = 0; reg < 16; ++reg) {
            int m = mrow0 + (reg & 3) + 8 * (reg >> 2);
            float p = __expf(sacc[nt][reg] - wm);
            if (m < TOK && j < 112) lh[PS + m * 120 + j] = (_Float16)p; // pad cols -> exact 0
        }
    }

    // ---------------- Stage 4: O = P V ; row-sums via MFMA against ones ------
    f32x16 oacc, osum;
#pragma unroll
    for (int i = 0; i < 16; i++) { oacc[i] = 0.f; osum[i] = 0.f; }

    half8 vones;
#pragma unroll
    for (int i = 0; i < 8; ++i) vones[i] = (_Float16)1.0f;

#pragma unroll
    for (int kk = 0; kk < 7; ++kk) {
        half8 pa = *(const half8*)&lh[PS + tok * 120 + kk * 16 + half * 8];
        half8 vf = *(const half8*)&lh[VT + t32 * VSTR + kk * 16 + half * 8];
        oacc = __builtin_amdgcn_mfma_f32_32x32x16_f16(pa, vf, oacc, 0, 0, 0);
        osum = __builtin_amdgcn_mfma_f32_32x32x16_f16(pa, vones, osum, 0, 0, 0);
    }

    if (useO16) {
        _Float16* ob = o16 + ((long)b * TOK) * 128 + h * 32 + t32;
#pragma unroll
        for (int reg = 0; reg < 16; ++reg) {
            int m = mrow0 + (reg & 3) + 8 * (reg >> 2);
            float inv = __builtin_amdgcn_rcpf(osum[reg]);
            if (m < TOK) ob[(long)m * 128] = (_Float16)(oacc[reg] * inv);
        }
    } else {
        float* ob = out + ((long)b * TOK) * 128 + h * 32 + t32;
#pragma unroll
        for (int reg = 0; reg < 16; ++reg) {
            int m = mrow0 + (reg & 3) + 8 * (reg >> 2);
            float inv = __builtin_amdgcn_rcpf(osum[reg]);
            if (m < TOK) ob[(long)m * 128] = oacc[reg] * inv;
        }
    }
}

// ---------------- Proj GEMM: A staged coalesced in LDS, W fp16 global -------
template <bool A16>
__global__ __launch_bounds__(256, 3) void proj_mfma(
    const void* __restrict__ Ain,       // fp16 o16 or fp32 out
    const _Float16* __restrict__ w16,   // [128][128] fp16
    const float* __restrict__ proj_b,   // [128]
    float* __restrict__ out,
    int totalRows)
{
    __shared__ __align__(16) _Float16 al[128 * 132];   // 33792 B

    const int tid  = threadIdx.x;
    const int wv   = tid >> 6;
    const int lane = tid & 63;
    const int t32  = lane & 31;
    const int half = lane >> 5;

    // coalesced staging of this block's 128 A rows as fp16
#pragma unroll
    for (int it = 0; it < 8; ++it) {
        int j = it * 256 + tid;           // 128 rows x 16 chunks
        int row = j >> 4, c8 = (j & 15) << 3;
        long gr = (long)blockIdx.x * 128 + row;
        if (gr >= totalRows) gr = totalRows - 1;
        if (A16) {
            *(half8*)&al[row * 132 + c8] =
                *(const half8*)((const _Float16*)Ain + gr * 128 + c8);
        } else {
            const float* src = (const float*)Ain + gr * 128 + c8;
            float4 a0 = *(const float4*)src;
            float4 a1 = *(const float4*)(src + 4);
            *(half8*)&al[row * 132 + c8] = cvt8(a0, a1);
        }
    }
    __syncthreads();

    half8 af[8];
#pragma unroll
    for (int kt = 0; kt < 8; ++kt)
        af[kt] = *(const half8*)&al[(32 * wv + t32) * 132 + kt * 16 + half * 8];

    f32x16 acc[4];
#pragma unroll
    for (int nt = 0; nt < 4; nt++)
#pragma unroll
        for (int i = 0; i < 16; i++) acc[nt][i] = 0.f;

#pragma unroll
    for (int kt = 0; kt < 8; ++kt) {
#pragma unroll
        for (int nt = 0; nt < 4; ++nt) {
            half8 bf = *(const half8*)(w16 + (long)(nt * 32 + t32) * 128 + kt * 16 + half * 8);
            acc[nt] = __builtin_amdgcn_mfma_f32_32x32x16_f16(af[kt], bf, acc[nt], 0, 0, 0);
        }
    }

    const long rowb = (long)blockIdx.x * 128 + 32 * wv;
#pragma unroll
    for (int nt = 0; nt < 4; ++nt) {
        int co = nt * 32 + t32;
        float pb = proj_b[co];
#pragma unroll
        for (int reg = 0; reg < 16; ++reg) {
            long m = rowb + (reg & 3) + 8 * (reg >> 2) + 4 * half;
            if (m < totalRows) out[m * 128 + co] = acc[nt][reg] + pb;
        }
    }
}

extern "C" void kernel_launch(void* const* d_in, const int* in_sizes, int n_in,
                              void* d_out, int out_size, void* d_ws, size_t ws_size,
                              hipStream_t stream) {
    const float* x      = (const float*)d_in[0];
    const float* mask   = (const float*)d_in[1];
    const float* qkv_w  = (const float*)d_in[2];
    const float* qkv_b  = (const float*)d_in[3];
    const float* rel    = (const float*)d_in[4];
    const float* proj_w = (const float*)d_in[5];
    const float* proj_b = (const float*)d_in[6];
    float* out = (float*)d_out;

    const int B     = in_sizes[0] / (TOK * 128);
    const int Lmask = in_sizes[1] / (TOK * TOK);
    const int totalRows = B * TOK;

    _Float16* w16  = (_Float16*)d_ws;        // 49152 qkv + 16384 proj halves
    _Float16* o16  = w16 + 65536;
    const size_t needO = 131072 + (size_t)totalRows * 128 * 2;
    const int useO16 = (ws_size >= needO) ? 1 : 0;

    prep_w<<<256, 256, 0, stream>>>(qkv_w, proj_w, w16);

    attn_mfma<<<B * 4, 256, 0, stream>>>(x, mask, qkv_b, rel, w16, out, o16,
                                         Lmask, useO16);

    const int grid = (totalRows + 127) / 128;
    if (useO16)
        proj_mfma<true><<<grid, 256, 0, stream>>>((const void*)o16, w16 + 49152,
                                                  proj_b, out, totalRows);
    else
        proj_mfma<false><<<grid, 256, 0, stream>>>((const void*)out, w16 + 49152,
                                                   proj_b, out, totalRows);
}

// Round 4
// 401.322 us; speedup vs baseline: 1.7162x; 1.1002x over previous
//
#include <hip/hip_runtime.h>

typedef __attribute__((ext_vector_type(8))) _Float16 half8;
typedef __attribute__((ext_vector_type(16))) float f32x16;

#define TOK 98
#define QSCALE 0.17677669529663687f  // 1/sqrt(32)

// LDS layout in _Float16 units — three overlaid phases:
//  Phase A (staging):     XL [98][132] at 0            (x as fp16)
//  Phase B (after bar#2): VT [32][132] at 0,  QS [98][40] at 4224, KS [98][40] at 8144
//  Phase C (after bar#4): PS [98][120] at 4224         (over dead Q,K)
#define XL   0
#define XSTR 132
#define VT   0
#define VSTR 132
#define QS   4224
#define KS   8144
#define PS   4224
#define PSTR 120
#define LDSH 15984   // halves = 31968 B (+ rel floats) -> 4 blocks/CU

__device__ inline half8 cvt8(float4 a, float4 b) {
    half8 r;
    r[0] = (_Float16)a.x; r[1] = (_Float16)a.y; r[2] = (_Float16)a.z; r[3] = (_Float16)a.w;
    r[4] = (_Float16)b.x; r[5] = (_Float16)b.y; r[6] = (_Float16)b.z; r[7] = (_Float16)b.w;
    return r;
}

// ---------------- Prep: fp32 -> fp16 weight conversion (once per call) ------
// w16[0..49152)    = qkv_w fp16
// w16[49152..65536)= proj_w fp16
__global__ void prep_w(const float* __restrict__ qkv_w,
                       const float* __restrict__ proj_w,
                       _Float16* __restrict__ w16)
{
    int i = blockIdx.x * 256 + threadIdx.x;   // grid exactly 65536 threads
    if (i < 49152) w16[i] = (_Float16)qkv_w[i];
    else           w16[i] = (_Float16)proj_w[i - 49152];
}

__global__ __launch_bounds__(256, 4) void attn_mfma(
    const float* __restrict__ x,       // [B][98][128]
    const float* __restrict__ mask,    // [L][98][98]
    const float* __restrict__ qkv_b,   // [384]
    const float* __restrict__ rel,     // [4][507]
    const _Float16* __restrict__ qkv16,// [384][128] fp16
    float* __restrict__ out,           // [B][98][128] (pre-proj, fp32 path)
    _Float16* __restrict__ o16,        // [B][98][128] fp16 (ws path)
    int Lmask, int useO16)
{
    __shared__ __align__(16) _Float16 lh[LDSH];
    __shared__ float rel_lds[507];

    const int tid  = threadIdx.x;

    // XCD-bijective swizzle (grid % 8 == 0 in this problem).
    int wg = (int)blockIdx.x;
    int work;
    if ((gridDim.x & 7) == 0) {
        int cpx = gridDim.x >> 3;
        work = (wg & 7) * cpx + (wg >> 3);
    } else {
        work = wg;
    }
    const int b    = work >> 2;
    const int h    = work & 3;

    const int wv   = tid >> 6;        // wave 0..3: owns token rows [32wv, 32wv+32)
    const int lane = tid & 63;
    const int t32  = lane & 31;
    const int half = lane >> 5;

    // ---- stage rel row (separate region); stage x fp16 coalesced into XL ----
    for (int i = tid; i < 507; i += 256) rel_lds[i] = rel[h * 507 + i];
    for (int j = tid; j < TOK * 16; j += 256) {
        int row = j >> 4, c8 = (j & 15) << 3;
        const float* src = x + ((long)b * TOK + row) * 128 + c8;
        float4 a0 = *(const float4*)src;
        float4 a1 = *(const float4*)(src + 4);
        *(half8*)&lh[XL + row * XSTR + c8] = cvt8(a0, a1);
    }
    __syncthreads();   // bar #1: XL ready

    // ---- preload A fragments (all XL reads happen here) ----
    int tok = 32 * wv + t32; if (tok > 97) tok = 97;   // clamp: dup rows discarded

    half8 af[8];
#pragma unroll
    for (int kt = 0; kt < 8; ++kt)
        af[kt] = *(const half8*)&lh[XL + tok * XSTR + kt * 16 + half * 8];

    __syncthreads();   // bar #2: XL dead -> Q/K/Vt region may be written

    // ---------------- Stage 1: qkv slice GEMM (A regs, B fp16 global) ----
    f32x16 acc[3];
#pragma unroll
    for (int nt = 0; nt < 3; nt++)
#pragma unroll
        for (int i = 0; i < 16; i++) acc[nt][i] = 0.f;

#pragma unroll
    for (int kt = 0; kt < 8; ++kt) {
#pragma unroll
        for (int nt = 0; nt < 3; nt++) {
            const _Float16* wr = qkv16 + ((long)(nt * 128 + h * 32 + t32)) * 128 + kt * 16 + half * 8;
            half8 bf = *(const half8*)wr;
            acc[nt] = __builtin_amdgcn_mfma_f32_32x32x16_f16(af[kt], bf, acc[nt], 0, 0, 0);
        }
    }

    // store Q (scaled+bias), K row-major; V transposed Vt[d][m].
    // C/D layout: col=lane&31, row=(reg&3)+8*(reg>>2)+4*half
    {
        const float qb = qkv_b[h * 32 + t32];
        const float kb = qkv_b[128 + h * 32 + t32];
        const float vb = qkv_b[256 + h * 32 + t32];
#pragma unroll
        for (int reg = 0; reg < 16; ++reg) {
            int m = 32 * wv + (reg & 3) + 8 * (reg >> 2) + 4 * half;
            if (m < TOK) {
                lh[QS + m * 40 + t32]   = (_Float16)((acc[0][reg] + qb) * QSCALE);
                lh[KS + m * 40 + t32]   = (_Float16)(acc[1][reg] + kb);
                lh[VT + t32 * VSTR + m] = (_Float16)(acc[2][reg] + vb);   // transposed
            }
        }
    }
    // zero Vt pad tokens 98..111 (PV k-padding) — VT region valid after bar#2
    for (int i = tid; i < 32 * 14; i += 256) {
        int d = i / 14, m = i - 14 * d;
        lh[VT + d * VSTR + 98 + m] = (_Float16)0.f;
    }

    // ---------------- Mask burst (unconditional, clamped addresses) ----------
    const long mbase = (long)(b % Lmask) * (TOK * TOK);
    const int mrow0 = 32 * wv + 4 * half;

    int jterm[4]; bool jvld[4];
    float mv[4][16];
#pragma unroll
    for (int nt = 0; nt < 4; ++nt) {
        int j = nt * 32 + t32;
        jvld[nt] = (j < TOK);
        int jc = jvld[nt] ? j : 97;
        int tj = jc / 49; int rj = jc - 49 * tj; int hj = rj / 7; int wj = rj - 7 * hj;
        jterm[nt] = tj * 169 + hj * 13 + wj;
        const float* mc = mask + mbase + jc;
#pragma unroll
        for (int reg = 0; reg < 16; ++reg) {
            int m = mrow0 + (reg & 3) + 8 * (reg >> 2);
            int mm = m > 97 ? 97 : m;
            mv[nt][reg] = mc[(long)mm * TOK];
        }
    }

    // ---- init S accumulator with bias+mask+validity (MFMA C-input) ----------
    // mv dies here, before sacc's long live range -> peak VGPR stays < 128.
    f32x16 sacc[4];
#pragma unroll
    for (int reg = 0; reg < 16; ++reg) {
        int m = mrow0 + (reg & 3) + 8 * (reg >> 2);
        bool mok = (m < TOK);
        int mm = mok ? m : 97;
        int ti = mm / 49; int r2 = mm - 49 * ti; int hi = r2 / 7; int wi = r2 - 7 * hi;
        // offset 253 = 1*169 + 6*13 + 6 so that mterm - jterm == REL_IDX[m][j]
        int mterm = ti * 169 + hi * 13 + wi + 253;
#pragma unroll
        for (int nt = 0; nt < 4; ++nt) {
            float s = -1e30f;
            if (mok && jvld[nt]) s = rel_lds[mterm - jterm[nt]] + mv[nt][reg];
            sacc[nt][reg] = s;
        }
    }

    __syncthreads();   // bar #3: Q/K/Vt visible to all waves

    // ---------------- Stage 2: S += Q K^T (accumulates onto bias init) -------
#pragma unroll
    for (int kk = 0; kk < 2; ++kk) {
        half8 qa = *(const half8*)&lh[QS + tok * 40 + kk * 16 + half * 8];
#pragma unroll
        for (int nt = 0; nt < 4; ++nt) {
            int kr = nt * 32 + t32; if (kr > 97) kr = 97;   // dup cols stay ~-1e30
            half8 kf = *(const half8*)&lh[KS + kr * 40 + kk * 16 + half * 8];
            sacc[nt] = __builtin_amdgcn_mfma_f32_32x32x16_f16(qa, kf, sacc[nt], 0, 0, 0);
        }
    }

    __syncthreads();   // bar #4: all Q/K reads done -> P may overlay them

    // ---------------- Stage 3: tile-max softmax ----------------
    float wm = -1e30f;
#pragma unroll
    for (int nt = 0; nt < 4; ++nt)
#pragma unroll
        for (int reg = 0; reg < 16; ++reg) wm = fmaxf(wm, sacc[nt][reg]);
    wm = fmaxf(wm, __shfl_xor(wm, 1));
    wm = fmaxf(wm, __shfl_xor(wm, 2));
    wm = fmaxf(wm, __shfl_xor(wm, 4));
    wm = fmaxf(wm, __shfl_xor(wm, 8));
    wm = fmaxf(wm, __shfl_xor(wm, 16));
    wm = fmaxf(wm, __shfl_xor(wm, 32));

#pragma unroll
    for (int nt = 0; nt < 4; ++nt) {
        int j = nt * 32 + t32;
#pragma unroll
        for (int reg = 0; reg < 16; ++reg) {
            int m = mrow0 + (reg & 3) + 8 * (reg >> 2);
            float p = __expf(sacc[nt][reg] - wm);
            if (m < TOK && j < 112) lh[PS + m * PSTR + j] = (_Float16)p; // pad cols -> exact 0
        }
    }

    // ---------------- Stage 4: O = P V ; row-sums via MFMA against ones ------
    f32x16 oacc, osum;
#pragma unroll
    for (int i = 0; i < 16; i++) { oacc[i] = 0.f; osum[i] = 0.f; }

    half8 vones;
#pragma unroll
    for (int i = 0; i < 8; ++i) vones[i] = (_Float16)1.0f;

#pragma unroll
    for (int kk = 0; kk < 7; ++kk) {
        half8 pa = *(const half8*)&lh[PS + tok * PSTR + kk * 16 + half * 8];
        half8 vf = *(const half8*)&lh[VT + t32 * VSTR + kk * 16 + half * 8];
        oacc = __builtin_amdgcn_mfma_f32_32x32x16_f16(pa, vf, oacc, 0, 0, 0);
        osum = __builtin_amdgcn_mfma_f32_32x32x16_f16(pa, vones, osum, 0, 0, 0);
    }

    if (useO16) {
        _Float16* ob = o16 + ((long)b * TOK) * 128 + h * 32 + t32;
#pragma unroll
        for (int reg = 0; reg < 16; ++reg) {
            int m = mrow0 + (reg & 3) + 8 * (reg >> 2);
            float inv = __builtin_amdgcn_rcpf(osum[reg]);
            if (m < TOK) ob[(long)m * 128] = (_Float16)(oacc[reg] * inv);
        }
    } else {
        float* ob = out + ((long)b * TOK) * 128 + h * 32 + t32;
#pragma unroll
        for (int reg = 0; reg < 16; ++reg) {
            int m = mrow0 + (reg & 3) + 8 * (reg >> 2);
            float inv = __builtin_amdgcn_rcpf(osum[reg]);
            if (m < TOK) ob[(long)m * 128] = oacc[reg] * inv;
        }
    }
}

// ---------------- Proj GEMM: A staged coalesced in LDS, W fp16 global -------
template <bool A16>
__global__ __launch_bounds__(256, 4) void proj_mfma(
    const void* __restrict__ Ain,       // fp16 o16 or fp32 out
    const _Float16* __restrict__ w16,   // [128][128] fp16
    const float* __restrict__ proj_b,   // [128]
    float* __restrict__ out,
    int totalRows)
{
    __shared__ __align__(16) _Float16 al[128 * 132];   // 33792 B -> 4 blocks/CU

    const int tid  = threadIdx.x;
    const int wv   = tid >> 6;
    const int lane = tid & 63;
    const int t32  = lane & 31;
    const int half = lane >> 5;

    // coalesced staging of this block's 128 A rows as fp16
#pragma unroll
    for (int it = 0; it < 8; ++it) {
        int j = it * 256 + tid;           // 128 rows x 16 chunks
        int row = j >> 4, c8 = (j & 15) << 3;
        long gr = (long)blockIdx.x * 128 + row;
        if (gr >= totalRows) gr = totalRows - 1;
        if (A16) {
            *(half8*)&al[row * 132 + c8] =
                *(const half8*)((const _Float16*)Ain + gr * 128 + c8);
        } else {
            const float* src = (const float*)Ain + gr * 128 + c8;
            float4 a0 = *(const float4*)src;
            float4 a1 = *(const float4*)(src + 4);
            *(half8*)&al[row * 132 + c8] = cvt8(a0, a1);
        }
    }
    __syncthreads();

    half8 af[8];
#pragma unroll
    for (int kt = 0; kt < 8; ++kt)
        af[kt] = *(const half8*)&al[(32 * wv + t32) * 132 + kt * 16 + half * 8];

    f32x16 acc[4];
#pragma unroll
    for (int nt = 0; nt < 4; nt++)
#pragma unroll
        for (int i = 0; i < 16; i++) acc[nt][i] = 0.f;

#pragma unroll
    for (int kt = 0; kt < 8; ++kt) {
#pragma unroll
        for (int nt = 0; nt < 4; ++nt) {
            half8 bf = *(const half8*)(w16 + (long)(nt * 32 + t32) * 128 + kt * 16 + half * 8);
            acc[nt] = __builtin_amdgcn_mfma_f32_32x32x16_f16(af[kt], bf, acc[nt], 0, 0, 0);
        }
    }

    const long rowb = (long)blockIdx.x * 128 + 32 * wv;
#pragma unroll
    for (int nt = 0; nt < 4; ++nt) {
        int co = nt * 32 + t32;
        float pb = proj_b[co];
#pragma unroll
        for (int reg = 0; reg < 16; ++reg) {
            long m = rowb + (reg & 3) + 8 * (reg >> 2) + 4 * half;
            if (m < totalRows) out[m * 128 + co] = acc[nt][reg] + pb;
        }
    }
}

extern "C" void kernel_launch(void* const* d_in, const int* in_sizes, int n_in,
                              void* d_out, int out_size, void* d_ws, size_t ws_size,
                              hipStream_t stream) {
    const float* x      = (const float*)d_in[0];
    const float* mask   = (const float*)d_in[1];
    const float* qkv_w  = (const float*)d_in[2];
    const float* qkv_b  = (const float*)d_in[3];
    const float* rel    = (const float*)d_in[4];
    const float* proj_w = (const float*)d_in[5];
    const float* proj_b = (const float*)d_in[6];
    float* out = (float*)d_out;

    const int B     = in_sizes[0] / (TOK * 128);
    const int Lmask = in_sizes[1] / (TOK * TOK);
    const int totalRows = B * TOK;

    _Float16* w16  = (_Float16*)d_ws;        // 49152 qkv + 16384 proj halves
    _Float16* o16  = w16 + 65536;
    const size_t needO = 131072 + (size_t)totalRows * 128 * 2;
    const int useO16 = (ws_size >= needO) ? 1 : 0;

    prep_w<<<256, 256, 0, stream>>>(qkv_w, proj_w, w16);

    attn_mfma<<<B * 4, 256, 0, stream>>>(x, mask, qkv_b, rel, w16, out, o16,
                                         Lmask, useO16);

    const int grid = (totalRows + 127) / 128;
    if (useO16)
        proj_mfma<true><<<grid, 256, 0, stream>>>((const void*)o16, w16 + 49152,
                                                  proj_b, out, totalRows);
    else
        proj_mfma<false><<<grid, 256, 0, stream>>>((const void*)out, w16 + 49152,
                                                   proj_b, out, totalRows);
}

// Round 5
// 356.491 us; speedup vs baseline: 1.9320x; 1.1258x over previous
//
#include <hip/hip_runtime.h>

typedef __attribute__((ext_vector_type(8))) _Float16 half8;
typedef __attribute__((ext_vector_type(16))) float f32x16;

#define TOK 98
#define QSCALE 0.17677669529663687f  // 1/sqrt(32)

// LDS layout in _Float16 units — three overlaid phases:
//  Phase A (staging):     XL [98][132] at 0            (x as fp16)
//  Phase B (after bar#2): VT [32][132] at 0,  QS [98][40] at 4224, KS [98][40] at 8144
//  Phase C (after bar#4): PS [98][120] at 4224         (over dead Q,K)
#define XL   0
#define XSTR 132
#define VT   0
#define VSTR 132
#define QS   4224
#define KS   8144
#define PS   4224
#define PSTR 120
#define LDSH 15984   // halves = 31968 B (+ rel floats) -> 4 blocks/CU

__device__ inline half8 cvt8(float4 a, float4 b) {
    half8 r;
    r[0] = (_Float16)a.x; r[1] = (_Float16)a.y; r[2] = (_Float16)a.z; r[3] = (_Float16)a.w;
    r[4] = (_Float16)b.x; r[5] = (_Float16)b.y; r[6] = (_Float16)b.z; r[7] = (_Float16)b.w;
    return r;
}

// ---------------- Prep: fp32 -> fp16 weights in MFMA-FRAGMENT order ---------
// qkv region  [0..49152):  idx = (((h*3+nt)*8 + kt)*64 + lane)*8 + e
//                          = qkv_w[(nt*128 + h*32 + t32)*128 + kt*16 + hf*8 + e]
// proj region [49152..65536): idx = ((nt*8 + kt)*64 + lane)*8 + e
//                          = proj_w[(nt*32 + t32)*128 + kt*16 + hf*8 + e]
// (lane = hf*32 + t32). B-fragment loads become 1KB fully-coalesced bursts.
__global__ void prep_w(const float* __restrict__ qkv_w,
                       const float* __restrict__ proj_w,
                       _Float16* __restrict__ w16)
{
    int i = blockIdx.x * 256 + threadIdx.x;   // grid exactly 65536 threads
    if (i < 49152) {
        int e = i & 7, lane = (i >> 3) & 63, kt = (i >> 9) & 7;
        int g = i >> 12;                  // g = h*3 + nt, 0..11
        int h = g / 3, nt = g - 3 * h;
        int t32 = lane & 31, hf = lane >> 5;
        w16[i] = (_Float16)qkv_w[(nt * 128 + h * 32 + t32) * 128 + kt * 16 + hf * 8 + e];
    } else {
        int j = i - 49152;
        int e = j & 7, lane = (j >> 3) & 63, kt = (j >> 9) & 7, nt = j >> 12;
        int t32 = lane & 31, hf = lane >> 5;
        w16[i] = (_Float16)proj_w[(nt * 32 + t32) * 128 + kt * 16 + hf * 8 + e];
    }
}

__global__ __launch_bounds__(256, 4) void attn_mfma(
    const float* __restrict__ x,       // [B][98][128]
    const float* __restrict__ mask,    // [L][98][98]
    const float* __restrict__ qkv_b,   // [384]
    const float* __restrict__ rel,     // [4][507]
    const _Float16* __restrict__ qkv16,// fragment-ordered qkv weights
    float* __restrict__ out,           // [B][98][128] (pre-proj, fp32 path)
    _Float16* __restrict__ o16,        // [B][98][128] fp16 (ws path)
    int Lmask, int useO16)
{
    __shared__ __align__(16) _Float16 lh[LDSH];
    __shared__ float rel_lds[507];

    const int tid  = threadIdx.x;

    // XCD-bijective swizzle (grid % 8 == 0 in this problem).
    int wg = (int)blockIdx.x;
    int work;
    if ((gridDim.x & 7) == 0) {
        int cpx = gridDim.x >> 3;
        work = (wg & 7) * cpx + (wg >> 3);
    } else {
        work = wg;
    }
    const int b    = work >> 2;
    const int h    = work & 3;

    const int wv   = tid >> 6;        // wave 0..3: owns token rows [32wv, 32wv+32)
    const int lane = tid & 63;
    const int t32  = lane & 31;
    const int half = lane >> 5;

    // ---- stage rel row (separate region); stage x fp16 coalesced into XL ----
    for (int i = tid; i < 507; i += 256) rel_lds[i] = rel[h * 507 + i];
    for (int j = tid; j < TOK * 16; j += 256) {
        int row = j >> 4, c8 = (j & 15) << 3;
        const float* src = x + ((long)b * TOK + row) * 128 + c8;
        float4 a0 = *(const float4*)src;
        float4 a1 = *(const float4*)(src + 4);
        *(half8*)&lh[XL + row * XSTR + c8] = cvt8(a0, a1);
    }
    __syncthreads();   // bar #1: XL ready

    // ---- preload A fragments (all XL reads happen here) ----
    int tok = 32 * wv + t32; if (tok > 97) tok = 97;   // clamp: dup rows discarded

    half8 af[8];
#pragma unroll
    for (int kt = 0; kt < 8; ++kt)
        af[kt] = *(const half8*)&lh[XL + tok * XSTR + kt * 16 + half * 8];

    __syncthreads();   // bar #2: XL dead -> Q/K/Vt region may be written

    // ---------------- Stage 1: qkv slice GEMM (A regs, B fragment-coalesced) --
    const _Float16* wbase = qkv16 + (long)h * 3 * 4096 + lane * 8;  // + (nt*8+kt)*512

    f32x16 acc[3];
#pragma unroll
    for (int nt = 0; nt < 3; nt++)
#pragma unroll
        for (int i = 0; i < 16; i++) acc[nt][i] = 0.f;

#pragma unroll
    for (int kt = 0; kt < 8; ++kt) {
#pragma unroll
        for (int nt = 0; nt < 3; nt++) {
            half8 bf = *(const half8*)(wbase + (nt * 8 + kt) * 512);
            acc[nt] = __builtin_amdgcn_mfma_f32_32x32x16_f16(af[kt], bf, acc[nt], 0, 0, 0);
        }
    }

    // store Q (scaled+bias), K row-major; V transposed Vt[d][m].
    // C/D layout: col=lane&31, row=(reg&3)+8*(reg>>2)+4*half
    {
        const float qb = qkv_b[h * 32 + t32];
        const float kb = qkv_b[128 + h * 32 + t32];
        const float vb = qkv_b[256 + h * 32 + t32];
#pragma unroll
        for (int reg = 0; reg < 16; ++reg) {
            int m = 32 * wv + (reg & 3) + 8 * (reg >> 2) + 4 * half;
            if (m < TOK) {
                lh[QS + m * 40 + t32]   = (_Float16)((acc[0][reg] + qb) * QSCALE);
                lh[KS + m * 40 + t32]   = (_Float16)(acc[1][reg] + kb);
                lh[VT + t32 * VSTR + m] = (_Float16)(acc[2][reg] + vb);   // transposed
            }
        }
    }
    // zero Vt pad tokens 98..111 (PV k-padding) — VT region valid after bar#2
    for (int i = tid; i < 32 * 14; i += 256) {
        int d = i / 14, m = i - 14 * d;
        lh[VT + d * VSTR + 98 + m] = (_Float16)0.f;
    }

    // ---------------- Mask burst (unconditional, clamped, coalesced) ---------
    const long mbase = (long)(b % Lmask) * (TOK * TOK);
    const int mrow0 = 32 * wv + 4 * half;

    int jterm[4]; bool jvld[4];
    float mv[4][16];
#pragma unroll
    for (int nt = 0; nt < 4; ++nt) {
        int j = nt * 32 + t32;
        jvld[nt] = (j < TOK);
        int jc = jvld[nt] ? j : 97;
        int tj = jc / 49; int rj = jc - 49 * tj; int hj = rj / 7; int wj = rj - 7 * hj;
        jterm[nt] = tj * 169 + hj * 13 + wj;
        const float* mc = mask + mbase + jc;
#pragma unroll
        for (int reg = 0; reg < 16; ++reg) {
            int m = mrow0 + (reg & 3) + 8 * (reg >> 2);
            int mm = m > 97 ? 97 : m;
            mv[nt][reg] = mc[(long)mm * TOK];
        }
    }

    __syncthreads();   // bar #3: Q/K/Vt visible; barrier wait covers mask latency

    // ---- init S accumulator with bias+mask+validity (MFMA C-input) ----------
    f32x16 sacc[4];
#pragma unroll
    for (int reg = 0; reg < 16; ++reg) {
        int m = mrow0 + (reg & 3) + 8 * (reg >> 2);
        bool mok = (m < TOK);
        int mm = mok ? m : 97;
        int ti = mm / 49; int r2 = mm - 49 * ti; int hi = r2 / 7; int wi = r2 - 7 * hi;
        // offset 253 = 1*169 + 6*13 + 6 so that mterm - jterm == REL_IDX[m][j]
        int mterm = ti * 169 + hi * 13 + wi + 253;
#pragma unroll
        for (int nt = 0; nt < 4; ++nt) {
            float s = -1e30f;
            if (mok && jvld[nt]) s = rel_lds[mterm - jterm[nt]] + mv[nt][reg];
            sacc[nt][reg] = s;
        }
    }

    // ---------------- Stage 2: S += Q K^T (accumulates onto bias init) -------
#pragma unroll
    for (int kk = 0; kk < 2; ++kk) {
        half8 qa = *(const half8*)&lh[QS + tok * 40 + kk * 16 + half * 8];
#pragma unroll
        for (int nt = 0; nt < 4; ++nt) {
            int kr = nt * 32 + t32; if (kr > 97) kr = 97;   // dup cols stay ~-1e30
            half8 kf = *(const half8*)&lh[KS + kr * 40 + kk * 16 + half * 8];
            sacc[nt] = __builtin_amdgcn_mfma_f32_32x32x16_f16(qa, kf, sacc[nt], 0, 0, 0);
        }
    }

    __syncthreads();   // bar #4: all Q/K reads done -> P may overlay them

    // ---------------- Stage 3: tile-max softmax ----------------
    float wm = -1e30f;
#pragma unroll
    for (int nt = 0; nt < 4; ++nt)
#pragma unroll
        for (int reg = 0; reg < 16; ++reg) wm = fmaxf(wm, sacc[nt][reg]);
    wm = fmaxf(wm, __shfl_xor(wm, 1));
    wm = fmaxf(wm, __shfl_xor(wm, 2));
    wm = fmaxf(wm, __shfl_xor(wm, 4));
    wm = fmaxf(wm, __shfl_xor(wm, 8));
    wm = fmaxf(wm, __shfl_xor(wm, 16));
    wm = fmaxf(wm, __shfl_xor(wm, 32));

#pragma unroll
    for (int nt = 0; nt < 4; ++nt) {
        int j = nt * 32 + t32;
#pragma unroll
        for (int reg = 0; reg < 16; ++reg) {
            int m = mrow0 + (reg & 3) + 8 * (reg >> 2);
            float p = __expf(sacc[nt][reg] - wm);
            if (m < TOK && j < 112) lh[PS + m * PSTR + j] = (_Float16)p; // pad cols -> exact 0
        }
    }

    // ---------------- Stage 4: O = P V ; row-sums via MFMA against ones ------
    f32x16 oacc, osum;
#pragma unroll
    for (int i = 0; i < 16; i++) { oacc[i] = 0.f; osum[i] = 0.f; }

    half8 vones;
#pragma unroll
    for (int i = 0; i < 8; ++i) vones[i] = (_Float16)1.0f;

#pragma unroll
    for (int kk = 0; kk < 7; ++kk) {
        half8 pa = *(const half8*)&lh[PS + tok * PSTR + kk * 16 + half * 8];
        half8 vf = *(const half8*)&lh[VT + t32 * VSTR + kk * 16 + half * 8];
        oacc = __builtin_amdgcn_mfma_f32_32x32x16_f16(pa, vf, oacc, 0, 0, 0);
        osum = __builtin_amdgcn_mfma_f32_32x32x16_f16(pa, vones, osum, 0, 0, 0);
    }

    if (useO16) {
        _Float16* ob = o16 + ((long)b * TOK) * 128 + h * 32 + t32;
#pragma unroll
        for (int reg = 0; reg < 16; ++reg) {
            int m = mrow0 + (reg & 3) + 8 * (reg >> 2);
            float inv = __builtin_amdgcn_rcpf(osum[reg]);
            if (m < TOK) ob[(long)m * 128] = (_Float16)(oacc[reg] * inv);
        }
    } else {
        float* ob = out + ((long)b * TOK) * 128 + h * 32 + t32;
#pragma unroll
        for (int reg = 0; reg < 16; ++reg) {
            int m = mrow0 + (reg & 3) + 8 * (reg >> 2);
            float inv = __builtin_amdgcn_rcpf(osum[reg]);
            if (m < TOK) ob[(long)m * 128] = oacc[reg] * inv;
        }
    }
}

// ---------------- Proj GEMM: A staged in LDS, W fragment-coalesced global ---
template <bool A16>
__global__ __launch_bounds__(256, 4) void proj_mfma(
    const void* __restrict__ Ain,       // fp16 o16 or fp32 out
    const _Float16* __restrict__ w16,   // fragment-ordered proj weights
    const float* __restrict__ proj_b,   // [128]
    float* __restrict__ out,
    int totalRows)
{
    __shared__ __align__(16) _Float16 al[128 * 132];   // 33792 B -> 4 blocks/CU

    const int tid  = threadIdx.x;
    const int wv   = tid >> 6;
    const int lane = tid & 63;
    const int t32  = lane & 31;
    const int half = lane >> 5;

    // coalesced staging of this block's 128 A rows as fp16
#pragma unroll
    for (int it = 0; it < 8; ++it) {
        int j = it * 256 + tid;           // 128 rows x 16 chunks
        int row = j >> 4, c8 = (j & 15) << 3;
        long gr = (long)blockIdx.x * 128 + row;
        if (gr >= totalRows) gr = totalRows - 1;
        if (A16) {
            *(half8*)&al[row * 132 + c8] =
                *(const half8*)((const _Float16*)Ain + gr * 128 + c8);
        } else {
            const float* src = (const float*)Ain + gr * 128 + c8;
            float4 a0 = *(const float4*)src;
            float4 a1 = *(const float4*)(src + 4);
            *(half8*)&al[row * 132 + c8] = cvt8(a0, a1);
        }
    }
    __syncthreads();

    half8 af[8];
#pragma unroll
    for (int kt = 0; kt < 8; ++kt)
        af[kt] = *(const half8*)&al[(32 * wv + t32) * 132 + kt * 16 + half * 8];

    const _Float16* wb = w16 + lane * 8;   // + (nt*8+kt)*512

    f32x16 acc[4];
#pragma unroll
    for (int nt = 0; nt < 4; nt++)
#pragma unroll
        for (int i = 0; i < 16; i++) acc[nt][i] = 0.f;

#pragma unroll
    for (int kt = 0; kt < 8; ++kt) {
#pragma unroll
        for (int nt = 0; nt < 4; ++nt) {
            half8 bf = *(const half8*)(wb + (nt * 8 + kt) * 512);
            acc[nt] = __builtin_amdgcn_mfma_f32_32x32x16_f16(af[kt], bf, acc[nt], 0, 0, 0);
        }
    }

    const long rowb = (long)blockIdx.x * 128 + 32 * wv;
#pragma unroll
    for (int nt = 0; nt < 4; ++nt) {
        int co = nt * 32 + t32;
        float pb = proj_b[co];
#pragma unroll
        for (int reg = 0; reg < 16; ++reg) {
            long m = rowb + (reg & 3) + 8 * (reg >> 2) + 4 * half;
            if (m < totalRows) out[m * 128 + co] = acc[nt][reg] + pb;
        }
    }
}

extern "C" void kernel_launch(void* const* d_in, const int* in_sizes, int n_in,
                              void* d_out, int out_size, void* d_ws, size_t ws_size,
                              hipStream_t stream) {
    const float* x      = (const float*)d_in[0];
    const float* mask   = (const float*)d_in[1];
    const float* qkv_w  = (const float*)d_in[2];
    const float* qkv_b  = (const float*)d_in[3];
    const float* rel    = (const float*)d_in[4];
    const float* proj_w = (const float*)d_in[5];
    const float* proj_b = (const float*)d_in[6];
    float* out = (float*)d_out;

    const int B     = in_sizes[0] / (TOK * 128);
    const int Lmask = in_sizes[1] / (TOK * TOK);
    const int totalRows = B * TOK;

    _Float16* w16  = (_Float16*)d_ws;        // 49152 qkv + 16384 proj halves
    _Float16* o16  = w16 + 65536;
    const size_t needO = 131072 + (size_t)totalRows * 128 * 2;
    const int useO16 = (ws_size >= needO) ? 1 : 0;

    prep_w<<<256, 256, 0, stream>>>(qkv_w, proj_w, w16);

    attn_mfma<<<B * 4, 256, 0, stream>>>(x, mask, qkv_b, rel, w16, out, o16,
                                         Lmask, useO16);

    const int grid = (totalRows + 127) / 128;
    if (useO16)
        proj_mfma<true><<<grid, 256, 0, stream>>>((const void*)o16, w16 + 49152,
                                                  proj_b, out, totalRows);
    else
        proj_mfma<false><<<grid, 256, 0, stream>>>((const void*)out, w16 + 49152,
                                                   proj_b, out, totalRows);
}